// Round 1
// baseline (778.517 us; speedup 1.0000x reference)
//
#include <hip/hip_runtime.h>
#include <math.h>

// Problem constants (from reference setup_inputs)
#define BB 64      // batches
#define NN 256     // sequence length
#define DD 64      // feature dim
#define TT 4096    // task pool size

// Tiling
#define NCH 4                  // t-chunks (blocks per batch)
#define CT (TT/NCH)            // 1024 tasks per block
#define THREADS 512
#define TPT (CT/THREADS)       // 2 tasks per thread
#define NB 16                  // data rows processed per GEMM group
#define WAVES (THREADS/64)     // 8
#define WG (NCH*WAVES)         // 32 wave-partials per (b,n)
#define BN (BB*NN)             // 16384 outputs

static_assert(TPT == 2, "layout assumes 2 tasks/thread");
static_assert(NN % NB == 0, "");

// Phase 1: per (batch, t-chunk) block. Sequential over n, keeping the
// cumulative log-prob c[t] in registers. Emits per-wave online-softmax
// partials (m, s, v) for every n BEFORE updating c with row n's logp,
// which matches alphas = cum[:, :-1]. For n==0, c==0 so the partial is
// the uniform average -> pred0 = mean_t z[0,t], same formula.
__global__ __launch_bounds__(THREADS)
void mmse_phase1(const float* __restrict__ data,
                 const float* __restrict__ targets,
                 const float* __restrict__ Wp,     // task_pool, (T, D) row-major
                 float* __restrict__ ws)
{
  const int bx   = blockIdx.x;
  const int b    = bx >> 2;      // batch
  const int ch   = bx & 3;       // t-chunk
  const int tid  = threadIdx.x;
  const int lane = tid & 63;
  const int wave = tid >> 6;
  const int wgid = ch * WAVES + wave;

  const int t0 = ch * CT + tid * TPT;
  const float* __restrict__ w0p = Wp + (size_t)t0 * DD;        // row t0
  const float* __restrict__ w1p = w0p + DD;                    // row t0+1
  const float* __restrict__ drow_base = data + (size_t)b * NN * DD;
  const float* __restrict__ tgt = targets + (size_t)b * NN;

  float* __restrict__ mplane = ws;
  float* __restrict__ splane = ws + (size_t)WG * BN;
  float* __restrict__ vplane = ws + (size_t)2 * WG * BN;

  float c0 = 0.f, c1 = 0.f;   // cumulative logp for this thread's 2 tasks

  #pragma unroll 1
  for (int g = 0; g < NN / NB; ++g) {
    const int n0 = g * NB;
    const float* __restrict__ drow = drow_base + (size_t)n0 * DD;

    float acc0[NB], acc1[NB];
    #pragma unroll
    for (int i = 0; i < NB; ++i) { acc0[i] = 0.f; acc1[i] = 0.f; }

    // z-GEMM for NB rows x 2 task columns, K = 64 split in two halves of 32
    #pragma unroll
    for (int half = 0; half < 2; ++half) {
      float4 wv0[8], wv1[8];
      #pragma unroll
      for (int q = 0; q < 8; ++q) {
        wv0[q] = *(const float4*)(w0p + half * 32 + q * 4);
        wv1[q] = *(const float4*)(w1p + half * 32 + q * 4);
      }
      #pragma unroll
      for (int q = 0; q < 8; ++q) {
        #pragma unroll
        for (int nb = 0; nb < NB; ++nb) {
          // block-uniform data operands -> scalar loads
          const float* dp = drow + nb * DD + half * 32 + q * 4;
          const float d0 = dp[0], d1 = dp[1], d2 = dp[2], d3 = dp[3];
          acc0[nb] = fmaf(d0, wv0[q].x, acc0[nb]);
          acc0[nb] = fmaf(d1, wv0[q].y, acc0[nb]);
          acc0[nb] = fmaf(d2, wv0[q].z, acc0[nb]);
          acc0[nb] = fmaf(d3, wv0[q].w, acc0[nb]);
          acc1[nb] = fmaf(d0, wv1[q].x, acc1[nb]);
          acc1[nb] = fmaf(d1, wv1[q].y, acc1[nb]);
          acc1[nb] = fmaf(d2, wv1[q].z, acc1[nb]);
          acc1[nb] = fmaf(d3, wv1[q].w, acc1[nb]);
        }
      }
    }

    // Sequential emit + state update for each of the NB rows
    #pragma unroll
    for (int nb = 0; nb < NB; ++nb) {
      const int n = n0 + nb;
      const float z0 = acc0[nb], z1 = acc1[nb];

      // local max, then wave max (6 shuffle steps)
      float ml = fmaxf(c0, c1);
      float m = ml;
      #pragma unroll
      for (int off = 1; off < 64; off <<= 1)
        m = fmaxf(m, __shfl_xor(m, off));

      float e0 = __expf(c0 - m);
      float e1 = __expf(c1 - m);
      float s = e0 + e1;
      float v = fmaf(e0, z0, e1 * z1);

      // wave sum of s and v
      #pragma unroll
      for (int off = 1; off < 64; off <<= 1) {
        s += __shfl_xor(s, off);
        v += __shfl_xor(v, off);
      }

      if (lane == 0) {
        const size_t o = (size_t)wgid * BN + (size_t)b * NN + n;
        mplane[o] = m;
        splane[o] = s;
        vplane[o] = v;
      }

      // update cumulative logp with row n (constant term cancels in softmax)
      const float tg = tgt[n];
      const float r0 = tg - z0;
      const float r1 = tg - z1;
      c0 = fmaf(r0, -0.5f * r0, c0);
      c1 = fmaf(r1, -0.5f * r1, c1);
    }
  }
}

// Phase 2: merge the WG=32 per-wave partials for each (b,n) output.
__global__ __launch_bounds__(256)
void mmse_phase2(const float* __restrict__ ws, float* __restrict__ out)
{
  const int idx = blockIdx.x * 256 + threadIdx.x;   // = b*NN + n
  const float* __restrict__ mp = ws;
  const float* __restrict__ sp = ws + (size_t)WG * BN;
  const float* __restrict__ vp = ws + (size_t)2 * WG * BN;

  float M = -INFINITY, S = 0.f, V = 0.f;
  #pragma unroll 1
  for (int wg = 0; wg < WG; ++wg) {
    const size_t o = (size_t)wg * BN + idx;
    const float m = mp[o], s = sp[o], v = vp[o];
    const float mn = fmaxf(M, m);
    const float ea = __expf(M - mn);   // exp(-inf)=0 handles the init
    const float eb = __expf(m - mn);
    S = fmaf(S, ea, s * eb);
    V = fmaf(V, ea, v * eb);
    M = mn;
  }
  out[idx] = V / S;
}

extern "C" void kernel_launch(void* const* d_in, const int* in_sizes, int n_in,
                              void* d_out, int out_size, void* d_ws, size_t ws_size,
                              hipStream_t stream)
{
  const float* data      = (const float*)d_in[0];   // (64,256,64)
  const float* targets   = (const float*)d_in[1];   // (64,256)
  const float* task_pool = (const float*)d_in[2];   // (4096,64,1) == (T,D)
  float* out = (float*)d_out;                       // (64,256)
  float* ws  = (float*)d_ws;                        // needs 3*WG*BN*4 = 6.3 MB

  hipLaunchKernelGGL(mmse_phase1, dim3(BB * NCH), dim3(THREADS), 0, stream,
                     data, targets, task_pool, ws);
  hipLaunchKernelGGL(mmse_phase2, dim3(BN / 256), dim3(256), 0, stream,
                     ws, out);
}

// Round 2
// 540.702 us; speedup vs baseline: 1.4398x; 1.4398x over previous
//
#include <hip/hip_runtime.h>
#include <math.h>

// Problem constants
#define BB 64      // batches
#define NN 256     // sequence length
#define DD 64      // feature dim
#define TT 4096    // task pool size

// Tiling
#define NCH 8                  // t-chunks (blocks per batch)
#define CT (TT/NCH)            // 512 tasks per block
#define THREADS 512            // 1 task per thread (TPT=1)
#define WAVES (THREADS/64)     // 8
#define NB 16                  // data rows per GEMM group
#define NGRP (NN/NB)           // 16
#define BN (BB*NN)             // 16384 outputs

typedef float f2 __attribute__((ext_vector_type(2)));

// DPP row_ror ctrl codes (rotate within each 16-lane row)
#define ROR1 0x121
#define ROR2 0x122
#define ROR4 0x124
#define ROR8 0x128
#define DPPF(x, C) __int_as_float(__builtin_amdgcn_update_dpp(0, __float_as_int(x), (C), 0xf, 0xf, true))

__device__ __forceinline__ float wave_max64(float x) {
  x = fmaxf(x, DPPF(x, ROR1));
  x = fmaxf(x, DPPF(x, ROR2));
  x = fmaxf(x, DPPF(x, ROR4));
  x = fmaxf(x, DPPF(x, ROR8));   // all 16 lanes of each row now hold row max
  x = fmaxf(x, __shfl_xor(x, 16));
  x = fmaxf(x, __shfl_xor(x, 32));
  return x;                       // all 64 lanes hold wave max
}
__device__ __forceinline__ float wave_sum64(float x) {
  x += DPPF(x, ROR1);
  x += DPPF(x, ROR2);
  x += DPPF(x, ROR4);
  x += DPPF(x, ROR8);
  x += __shfl_xor(x, 16);
  x += __shfl_xor(x, 32);
  return x;
}

// Phase 1: block = (batch b, t-chunk ch of 512 tasks). Each thread owns ONE
// task column. Sequential over n in groups of NB=16 rows:
//   GEMM (packed f32, data operands are block-uniform -> scalar loads),
//   then the 16-row c trajectory (cheap serial FMA), then 16 INDEPENDENT
//   per-row softmax partial reductions (DPP butterflies), LDS-merge the 8
//   waves' partials, one (m,s,v) triple per (row, chunk) to global.
// Emitting with c BEFORE the row's logp update == alphas = cum[:, :-1];
// n=0 gives the uniform average == pred0.  The -0.5*log(2*pi) term is
// uniform over t and cancels in softmax.
__global__ __launch_bounds__(THREADS, 4)
void mmse_phase1(const float* __restrict__ data,
                 const float* __restrict__ targets,
                 const float* __restrict__ Wp,     // (T, D) row-major
                 float* __restrict__ part)         // (BN, NCH, 3)
{
  const int bx   = blockIdx.x;
  const int b    = bx >> 3;
  const int ch   = bx & 7;
  const int tid  = threadIdx.x;
  const int lane = tid & 63;
  const int wave = tid >> 6;

  const int t0 = ch * CT + tid;
  const float* __restrict__ wrow  = Wp + (size_t)t0 * DD;
  const float* __restrict__ dbase = data + (size_t)b * NN * DD;
  const float* __restrict__ tgt   = targets + (size_t)b * NN;

  __shared__ float sbuf[2][WAVES][NB][4];   // double-buffered wave partials

  float c_run = 0.f;

  #pragma unroll 1
  for (int g = 0; g < NGRP; ++g) {
    const int n0 = g * NB;
    const float* __restrict__ drow = dbase + (size_t)n0 * DD;

    f2 acc[NB];
    #pragma unroll
    for (int i = 0; i < NB; ++i) acc[i] = (f2)(0.f);

    // z-GEMM: 16 rows x 1 task, K=64 in chunks of 16
    #pragma unroll
    for (int kc = 0; kc < 4; ++kc) {
      const f2* __restrict__ wp2 = (const f2*)(wrow + kc * 16);
      f2 wv[8];
      #pragma unroll
      for (int q = 0; q < 8; ++q) wv[q] = wp2[q];
      #pragma unroll
      for (int nb = 0; nb < NB; ++nb) {
        const f2* __restrict__ dp2 = (const f2*)(drow + nb * DD + kc * 16);
        #pragma unroll
        for (int q = 0; q < 8; ++q)
          acc[nb] += dp2[q] * wv[q];        // v_pk_fma_f32, scalar d operand
      }
    }

    // c trajectory for the 16 rows (cpre[nb] = cum BEFORE row n0+nb)
    float z[NB], cpre[NB];
    float c = c_run;
    #pragma unroll
    for (int nb = 0; nb < NB; ++nb) {
      z[nb]    = acc[nb].x + acc[nb].y;
      cpre[nb] = c;
      const float r = tgt[n0 + nb] - z[nb];
      c = fmaf(r, -0.5f * r, c);
    }
    c_run = c;

    // 16 independent per-row wave reductions
    #pragma unroll
    for (int nb = 0; nb < NB; ++nb) {
      const float m = wave_max64(cpre[nb]);
      const float e = __expf(cpre[nb] - m);
      const float s = wave_sum64(e);
      const float v = wave_sum64(e * z[nb]);
      if (lane == 0) {
        sbuf[g & 1][wave][nb][0] = m;
        sbuf[g & 1][wave][nb][1] = s;
        sbuf[g & 1][wave][nb][2] = v;
      }
    }
    __syncthreads();

    // merge the 8 wave partials; wave w handles rows 2w, 2w+1 (lanes 0,1)
    if (lane < 2) {
      const int row = wave * 2 + lane;
      float M = sbuf[g & 1][0][row][0];
      float S = sbuf[g & 1][0][row][1];
      float V = sbuf[g & 1][0][row][2];
      #pragma unroll
      for (int w8 = 1; w8 < WAVES; ++w8) {
        const float m2 = sbuf[g & 1][w8][row][0];
        const float s2 = sbuf[g & 1][w8][row][1];
        const float v2 = sbuf[g & 1][w8][row][2];
        const float mn = fmaxf(M, m2);
        const float ea = __expf(M - mn);
        const float eb = __expf(m2 - mn);
        S = fmaf(S, ea, s2 * eb);
        V = fmaf(V, ea, v2 * eb);
        M = mn;
      }
      const size_t o = ((size_t)(b * NN + n0 + row) * NCH + ch) * 3;
      part[o]     = M;
      part[o + 1] = S;
      part[o + 2] = V;
    }
  }
}

// Phase 2: merge the NCH=8 chunk partials per output (contiguous 96B reads).
__global__ __launch_bounds__(256)
void mmse_phase2(const float* __restrict__ part, float* __restrict__ out)
{
  const int idx = blockIdx.x * 256 + threadIdx.x;   // = b*NN + n
  const float* __restrict__ p = part + (size_t)idx * NCH * 3;
  float M = p[0], S = p[1], V = p[2];
  #pragma unroll
  for (int chn = 1; chn < NCH; ++chn) {
    const float m2 = p[chn * 3], s2 = p[chn * 3 + 1], v2 = p[chn * 3 + 2];
    const float mn = fmaxf(M, m2);
    const float ea = __expf(M - mn);
    const float eb = __expf(m2 - mn);
    S = fmaf(S, ea, s2 * eb);
    V = fmaf(V, ea, v2 * eb);
    M = mn;
  }
  out[idx] = V / S;
}

extern "C" void kernel_launch(void* const* d_in, const int* in_sizes, int n_in,
                              void* d_out, int out_size, void* d_ws, size_t ws_size,
                              hipStream_t stream)
{
  const float* data      = (const float*)d_in[0];   // (64,256,64)
  const float* targets   = (const float*)d_in[1];   // (64,256)
  const float* task_pool = (const float*)d_in[2];   // (4096,64,1) == (T,D)
  float* out  = (float*)d_out;                      // (64,256)
  float* part = (float*)d_ws;                       // BN*NCH*3*4 = 1.57 MB

  hipLaunchKernelGGL(mmse_phase1, dim3(BB * NCH), dim3(THREADS), 0, stream,
                     data, targets, task_pool, part);
  hipLaunchKernelGGL(mmse_phase2, dim3(BN / 256), dim3(256), 0, stream,
                     part, out);
}

// Round 3
// 130.361 us; speedup vs baseline: 5.9720x; 4.1477x over previous
//
#include <hip/hip_runtime.h>
#include <math.h>

// Problem constants
#define BB 64      // batches
#define NN 256     // sequence length
#define DD 64      // feature dim
#define TT 4096    // task pool size

// Tiling
#define NCH 16                 // t-chunks (blocks per batch)
#define CT (TT/NCH)            // 256 tasks per block
#define THREADS 512
#define WAVES 8                // each wave owns 32 tasks (2 MFMA tiles)
#define NB 16                  // n rows per group (one MFMA col-tile)
#define NGRP (NN/NB)           // 16
#define BN (BB*NN)             // 16384 outputs

typedef __bf16 bf16x8 __attribute__((ext_vector_type(8)));
typedef float  f32x4  __attribute__((ext_vector_type(4)));

// DPP ctrl codes
#define SHR1 0x111
#define SHR2 0x112
#define SHR4 0x114
#define SHR8 0x118
#define ROR1 0x121
#define ROR2 0x122
#define ROR4 0x124
#define ROR8 0x128

template<int C>
__device__ __forceinline__ float dppf(float x) {
  return __int_as_float(__builtin_amdgcn_update_dpp(
      0, __float_as_int(x), C, 0xf, 0xf, true));
}

__device__ __forceinline__ unsigned short f2bf(float f) {  // RNE f32->bf16
  unsigned int u = __float_as_uint(f);
  unsigned int r = u + 0x7FFFu + ((u >> 16) & 1u);
  return (unsigned short)(r >> 16);
}
__device__ __forceinline__ float bf2f(unsigned short h) {
  return __uint_as_float(((unsigned int)h) << 16);
}

union FragU { unsigned int u[4]; bf16x8 v; };

// Merge the 8 wave-partials of one group (all lanes compute, lanes<16 write)
__device__ __forceinline__ void merge8(const float4 (*sb)[16], int lane,
                                       float* __restrict__ part, size_t obase) {
  const int col = lane & 15;
  float4 p0 = sb[0][col];
  float M = p0.x, S = p0.y, V = p0.z;
  #pragma unroll
  for (int w = 1; w < WAVES; ++w) {
    float4 pw = sb[w][col];
    float mn = fmaxf(M, pw.x);
    float ea = __expf(M - mn), eb = __expf(pw.x - mn);
    S = fmaf(S, ea, pw.y * eb);
    V = fmaf(V, ea, pw.z * eb);
    M = mn;
  }
  if (lane < 16) {
    const size_t o = (obase + col) * 3;
    part[o] = M; part[o + 1] = S; part[o + 2] = V;
  }
}

// Phase 1: block = (batch b, chunk of 256 tasks). bf16x3 MFMA computes
// z[t, n] tiles (tasks on C-rows, n on C-cols). Per group of 16 n-cols:
// logp scan over cols via DPP row_shr (exclusive) gives alphas = cum[:, :-1];
// row_ror butterfly gives the group total for the carry. Softmax over t
// reduces 8 regs + shfl_xor(16,32); 8 waves merge via LDS; 16 chunks merge
// in phase 2. The -0.5*log(2*pi) term is uniform over t and cancels.
__global__ __launch_bounds__(THREADS, 4)
void mmse_phase1(const float* __restrict__ data,
                 const float* __restrict__ targets,
                 const float* __restrict__ Wp,     // (T, D) row-major
                 float* __restrict__ part)         // (NCH, BN, 3)
{
  const int bx   = blockIdx.x;
  const int b    = bx >> 4;
  const int ch   = bx & 15;
  const int tid  = threadIdx.x;
  const int lane = tid & 63;
  const int wave = tid >> 6;

  __shared__ unsigned int sDH[2][2][64][4];   // data frags hi (buf, kstep, lane, jpair)
  __shared__ unsigned int sDL[2][2][64][4];   // data frags lo
  __shared__ float4 sbuf[2][WAVES][16];       // wave partials (m,s,v)

  // ---- W fragments -> registers (hi/lo), A-layout: row=l&15, k=(l>>4)*8+j ----
  bf16x8 aH[2][2], aL[2][2];
  {
    const int tb = ch * CT + wave * 32;
    #pragma unroll
    for (int tile = 0; tile < 2; ++tile) {
      #pragma unroll
      for (int s = 0; s < 2; ++s) {
        const int row = tb + tile * 16 + (lane & 15);
        const int kb  = s * 32 + (lane >> 4) * 8;
        const float* wp = Wp + (size_t)row * DD + kb;
        FragU hu, lu;
        #pragma unroll
        for (int jj = 0; jj < 4; ++jj) {
          const float f0 = wp[2 * jj], f1 = wp[2 * jj + 1];
          const unsigned short h0 = f2bf(f0), h1 = f2bf(f1);
          const unsigned short g0 = f2bf(f0 - bf2f(h0)), g1 = f2bf(f1 - bf2f(h1));
          hu.u[jj] = (unsigned int)h0 | ((unsigned int)h1 << 16);
          lu.u[jj] = (unsigned int)g0 | ((unsigned int)g1 << 16);
        }
        aH[tile][s] = hu.v; aL[tile][s] = lu.v;
      }
    }
  }

  const float* __restrict__ dbase = data + (size_t)b * NN * DD;
  // staging coords for this thread: n row + 2-elem k slot
  const int sn = tid >> 5, sk2 = tid & 31;
  const int ss = sk2 >> 4, sjp = sk2 & 3;
  const int sl = ((sk2 >> 2) & 3) * 16 + sn;

  // stage group 0
  {
    const float2 q0 = *(const float2*)(dbase + (size_t)sn * DD + sk2 * 2);
    const unsigned short h0 = f2bf(q0.x), h1 = f2bf(q0.y);
    const unsigned short g0 = f2bf(q0.x - bf2f(h0)), g1 = f2bf(q0.y - bf2f(h1));
    sDH[0][ss][sl][sjp] = (unsigned int)h0 | ((unsigned int)h1 << 16);
    sDL[0][ss][sl][sjp] = (unsigned int)g0 | ((unsigned int)g1 << 16);
  }
  __syncthreads();

  float c8[2][4];
  #pragma unroll
  for (int t8 = 0; t8 < 8; ++t8) c8[t8 >> 2][t8 & 3] = 0.f;

  const size_t obase0 = (size_t)ch * BN + (size_t)b * NN;

  #pragma unroll 1
  for (int g = 0; g < NGRP; ++g) {
    const int buf = g & 1;
    // B-fragment reads (lane-contiguous b128, conflict-free)
    bf16x8 bh0 = *(const bf16x8*)&sDH[buf][0][lane][0];
    bf16x8 bh1 = *(const bf16x8*)&sDH[buf][1][lane][0];
    bf16x8 bl0 = *(const bf16x8*)&sDL[buf][0][lane][0];
    bf16x8 bl1 = *(const bf16x8*)&sDL[buf][1][lane][0];

    // prefetch next group's data (global -> regs; consumed after compute)
    float2 q;
    if (g + 1 < NGRP)
      q = *(const float2*)(dbase + (size_t)((g + 1) * NB + sn) * DD + sk2 * 2);

    // merge previous group's wave partials (round-robin wave)
    if (g > 0 && wave == ((g - 1) & 7))
      merge8(sbuf[(g - 1) & 1], lane, part, obase0 + (size_t)(g - 1) * NB);

    // bf16x3 MFMA: z = dHi*wHi + dLo*wHi + dHi*wLo
    f32x4 zz[2];
    zz[0] = (f32x4)(0.f); zz[1] = (f32x4)(0.f);
    zz[0] = __builtin_amdgcn_mfma_f32_16x16x32_bf16(aH[0][0], bh0, zz[0], 0, 0, 0);
    zz[0] = __builtin_amdgcn_mfma_f32_16x16x32_bf16(aH[0][0], bl0, zz[0], 0, 0, 0);
    zz[0] = __builtin_amdgcn_mfma_f32_16x16x32_bf16(aL[0][0], bh0, zz[0], 0, 0, 0);
    zz[0] = __builtin_amdgcn_mfma_f32_16x16x32_bf16(aH[0][1], bh1, zz[0], 0, 0, 0);
    zz[0] = __builtin_amdgcn_mfma_f32_16x16x32_bf16(aH[0][1], bl1, zz[0], 0, 0, 0);
    zz[0] = __builtin_amdgcn_mfma_f32_16x16x32_bf16(aL[0][1], bh1, zz[0], 0, 0, 0);
    zz[1] = __builtin_amdgcn_mfma_f32_16x16x32_bf16(aH[1][0], bh0, zz[1], 0, 0, 0);
    zz[1] = __builtin_amdgcn_mfma_f32_16x16x32_bf16(aH[1][0], bl0, zz[1], 0, 0, 0);
    zz[1] = __builtin_amdgcn_mfma_f32_16x16x32_bf16(aL[1][0], bh0, zz[1], 0, 0, 0);
    zz[1] = __builtin_amdgcn_mfma_f32_16x16x32_bf16(aH[1][1], bh1, zz[1], 0, 0, 0);
    zz[1] = __builtin_amdgcn_mfma_f32_16x16x32_bf16(aH[1][1], bl1, zz[1], 0, 0, 0);
    zz[1] = __builtin_amdgcn_mfma_f32_16x16x32_bf16(aL[1][1], bh1, zz[1], 0, 0, 0);

    // ---- per-group softmax machinery ----
    const float tg = targets[(size_t)b * NN + g * NB + (lane & 15)];
    float alpha[8];
    float mloc = -3.4e38f;
    #pragma unroll
    for (int t8 = 0; t8 < 8; ++t8) {
      const int tile = t8 >> 2, r = t8 & 3;
      const float z = zz[tile][r];
      const float resid = tg - z;
      const float lp = resid * (resid * -0.5f);
      // exclusive prefix over the 16 cols: shift then Hillis-Steele
      float x = dppf<SHR1>(lp);
      x += dppf<SHR1>(x);
      x += dppf<SHR2>(x);
      x += dppf<SHR4>(x);
      x += dppf<SHR8>(x);
      // group total (all 16 lanes) via ror butterfly
      float tot = lp;
      tot += dppf<ROR1>(tot);
      tot += dppf<ROR2>(tot);
      tot += dppf<ROR4>(tot);
      tot += dppf<ROR8>(tot);
      const float a_ = c8[tile][r] + x;
      alpha[t8] = a_;
      c8[tile][r] += tot;
      mloc = fmaxf(mloc, a_);
    }
    float m = fmaxf(mloc, __shfl_xor(mloc, 16));
    m = fmaxf(m, __shfl_xor(m, 32));
    float sv = 0.f, vv = 0.f;
    #pragma unroll
    for (int t8 = 0; t8 < 8; ++t8) {
      const float p = __expf(alpha[t8] - m);
      sv += p;
      vv = fmaf(p, zz[t8 >> 2][t8 & 3], vv);
    }
    sv += __shfl_xor(sv, 16); sv += __shfl_xor(sv, 32);
    vv += __shfl_xor(vv, 16); vv += __shfl_xor(vv, 32);
    if (lane < 16) sbuf[buf][wave][lane] = make_float4(m, sv, vv, 0.f);

    // stage-write next group into the other buffer
    if (g + 1 < NGRP) {
      const unsigned short h0 = f2bf(q.x), h1 = f2bf(q.y);
      const unsigned short g0 = f2bf(q.x - bf2f(h0)), g1 = f2bf(q.y - bf2f(h1));
      sDH[buf ^ 1][ss][sl][sjp] = (unsigned int)h0 | ((unsigned int)h1 << 16);
      sDL[buf ^ 1][ss][sl][sjp] = (unsigned int)g0 | ((unsigned int)g1 << 16);
    }
    __syncthreads();
  }

  // final group's merge
  if (wave == ((NGRP - 1) & 7))
    merge8(sbuf[(NGRP - 1) & 1], lane, part, obase0 + (size_t)(NGRP - 1) * NB);
}

// Phase 2: merge the NCH=16 chunk partials per output.
__global__ __launch_bounds__(256)
void mmse_phase2(const float* __restrict__ part, float* __restrict__ out)
{
  const int idx = blockIdx.x * 256 + threadIdx.x;   // = b*NN + n
  float M = -3.4e38f, S = 0.f, V = 0.f;
  #pragma unroll
  for (int ch = 0; ch < NCH; ++ch) {
    const size_t o = ((size_t)ch * BN + idx) * 3;
    const float m2 = part[o], s2 = part[o + 1], v2 = part[o + 2];
    const float mn = fmaxf(M, m2);
    const float ea = __expf(M - mn), eb = __expf(m2 - mn);
    S = fmaf(S, ea, s2 * eb);
    V = fmaf(V, ea, v2 * eb);
    M = mn;
  }
  out[idx] = V / S;
}

extern "C" void kernel_launch(void* const* d_in, const int* in_sizes, int n_in,
                              void* d_out, int out_size, void* d_ws, size_t ws_size,
                              hipStream_t stream)
{
  const float* data      = (const float*)d_in[0];   // (64,256,64)
  const float* targets   = (const float*)d_in[1];   // (64,256)
  const float* task_pool = (const float*)d_in[2];   // (4096,64,1) == (T,D)
  float* out  = (float*)d_out;                      // (64,256)
  float* part = (float*)d_ws;                       // NCH*BN*3*4 = 3.1 MB

  hipLaunchKernelGGL(mmse_phase1, dim3(BB * NCH), dim3(THREADS), 0, stream,
                     data, targets, task_pool, part);
  hipLaunchKernelGGL(mmse_phase2, dim3(BN / 256), dim3(256), 0, stream,
                     part, out);
}

// Round 5
// 122.235 us; speedup vs baseline: 6.3690x; 1.0665x over previous
//
#include <hip/hip_runtime.h>
#include <math.h>

// Problem constants
#define BB 64      // batches
#define NN 256     // sequence length
#define DD 64      // feature dim
#define TT 4096    // task pool size

// Tiling
#define NCH 16                 // t-chunks (blocks per batch)
#define CT (TT/NCH)            // 256 tasks per block
#define THREADS 512
#define WAVES 8                // each wave owns 32 tasks (2 MFMA row-tiles)
#define NB 16                  // n rows per group
#define NGRP (NN/NB)           // 16
#define BN (BB*NN)             // 16384 outputs

#define TILE_BYTES 4096                      // hi 2048 | lo 2048, swizzled [16n][64k] bf16
#define TILES_BYTES ((size_t)BB*NGRP*TILE_BYTES)   // 4 MB

#define NHL2E (-0.72134752044448170368f)     // -0.5 * log2(e)

typedef __bf16 bf16x8 __attribute__((ext_vector_type(8)));
typedef float  f32x4  __attribute__((ext_vector_type(4)));

// DPP row_shr ctrl codes
#define SHR1 0x111
#define SHR2 0x112
#define SHR4 0x114
#define SHR8 0x118

template<int C>
__device__ __forceinline__ float dppf(float x) {
  return __int_as_float(__builtin_amdgcn_update_dpp(
      0, __float_as_int(x), C, 0xf, 0xf, true));
}

// broadcast lane15 of each 16-lane group (BitMode: and=0x10, or=0xF)
__device__ __forceinline__ float bcast15(float x) {
  return __int_as_float(__builtin_amdgcn_ds_swizzle(__float_as_int(x), 0x1F0));
}

__device__ __forceinline__ unsigned short f2bf(float f) {  // RNE f32->bf16
  unsigned int u = __float_as_uint(f);
  unsigned int r = u + 0x7FFFu + ((u >> 16) & 1u);
  return (unsigned short)(r >> 16);
}
__device__ __forceinline__ float bf2f(unsigned short h) {
  return __uint_as_float(((unsigned int)h) << 16);
}

#define GLOAD_LDS16(gp, lp_) \
  __builtin_amdgcn_global_load_lds((const __attribute__((address_space(1))) void*)(gp), \
                                   (__attribute__((address_space(3))) void*)(lp_), 16, 0, 0)

union FragU { unsigned int u[4]; bf16x8 v; };

// ---------------------------------------------------------------------------
// Phase 0: data (f32) -> per-(b,group) swizzled bf16 hi/lo tile images.
// Image logical layout [16 n][64 k] bf16 (128 B/row); physical byte =
// logical ^ ((n&7)<<4) so phase1's ds_read_b128 fragments are conflict-free.
// One thread converts one float2 (2 consecutive k).
__global__ __launch_bounds__(256)
void mmse_phase0(const float* __restrict__ data, unsigned char* __restrict__ tiles)
{
  const int e  = blockIdx.x * 256 + threadIdx.x;   // pair index
  const int k2 = e & 31;
  const int n  = (e >> 5) & 255;
  const int b  = e >> 13;
  const float2 q = ((const float2*)data)[e];
  const unsigned short h0 = f2bf(q.x), h1 = f2bf(q.y);
  const unsigned short g0 = f2bf(q.x - bf2f(h0)), g1 = f2bf(q.y - bf2f(h1));
  const int nr = n & 15;
  const int logical = nr * 128 + k2 * 4;
  const int phys = logical ^ ((nr & 7) << 4);
  unsigned char* tp = tiles + (size_t)(b * NGRP + (n >> 4)) * TILE_BYTES;
  *(unsigned int*)(tp + phys)        = (unsigned int)h0 | ((unsigned int)h1 << 16);
  *(unsigned int*)(tp + 2048 + phys) = (unsigned int)g0 | ((unsigned int)g1 << 16);
}

// Merge the 8 wave-partials (packed L = m + log2 s, R = v/s) of one group.
// obase = pair index of (b, n0, ch) in part.
__device__ __forceinline__ void merge8(const float2 (*sb)[16], int lane,
                                       float* __restrict__ part, size_t obase) {
  const int col = lane & 15;
  float2 p0 = sb[0][col];
  float M = p0.x, S = 1.f, V = p0.y;
  #pragma unroll
  for (int w = 1; w < WAVES; ++w) {
    float2 pw = sb[w][col];
    float mn = fmaxf(M, pw.x);
    float ea = __builtin_amdgcn_exp2f(M - mn);
    float eb = __builtin_amdgcn_exp2f(pw.x - mn);
    S = S * ea + eb;
    V = fmaf(V, ea, pw.y * eb);
    M = mn;
  }
  if (lane < 16) {
    const size_t o = (obase + (size_t)col * NCH) * 2;
    part[o]     = M + __log2f(S);
    part[o + 1] = V / S;
  }
}

// ---------------------------------------------------------------------------
// Phase 1: block = (batch b, chunk of 256 tasks). Tasks on MFMA C-rows,
// n on C-cols. All log-probs in log2 space (exact for softmax). Per group:
// inclusive DPP scan over the 16 n-cols, exclusive = incl - lp, group total
// via ds_swizzle lane15-broadcast; softmax over the wave's 32 tasks via
// in-reg + shfl_xor(16,32); 8 waves merge via LDS; chunks merge in phase 2.
__global__ __launch_bounds__(THREADS, 4)
void mmse_phase1(const unsigned char* __restrict__ tiles,
                 const float* __restrict__ targets,
                 const float* __restrict__ Wp,     // (T, D) row-major
                 float* __restrict__ part)         // (BN, NCH, 2)
{
  const int bx   = blockIdx.x;
  const int b    = bx >> 4;
  const int ch   = bx & 15;
  const int tid  = threadIdx.x;
  const int lane = tid & 63;
  const int wave = tid >> 6;

  __shared__ uint4  dbufq[2][256];          // 2 x 4 KB swizzled tile images
  __shared__ float  tgl[NN];                // targets for this batch
  __shared__ float2 sbuf[2][WAVES][16];     // wave partials (L, R)

  unsigned char* dbufc = (unsigned char*)dbufq;

  // ---- W fragments -> registers (hi/lo). A-layout: row=l&15, k=(l>>4)*8+j
  bf16x8 aH[2][2], aL[2][2];
  {
    const int tb = ch * CT + wave * 32;
    #pragma unroll
    for (int tile = 0; tile < 2; ++tile) {
      #pragma unroll
      for (int s = 0; s < 2; ++s) {
        const int row = tb + tile * 16 + (lane & 15);
        const int kb  = s * 32 + (lane >> 4) * 8;
        const float* wp = Wp + (size_t)row * DD + kb;
        FragU hu, lu;
        #pragma unroll
        for (int jj = 0; jj < 4; ++jj) {
          const float f0 = wp[2 * jj], f1 = wp[2 * jj + 1];
          const unsigned short h0 = f2bf(f0), h1 = f2bf(f1);
          const unsigned short g0 = f2bf(f0 - bf2f(h0)), g1 = f2bf(f1 - bf2f(h1));
          hu.u[jj] = (unsigned int)h0 | ((unsigned int)h1 << 16);
          lu.u[jj] = (unsigned int)g0 | ((unsigned int)g1 << 16);
        }
        aH[tile][s] = hu.v; aL[tile][s] = lu.v;
      }
    }
  }

  // stage targets (1 KB) and tile 0 via async global->LDS
  if (wave == 0)
    GLOAD_LDS16(targets + (size_t)b * NN + lane * 4, tgl);
  if (wave < 4)
    GLOAD_LDS16(tiles + (size_t)(b * NGRP) * TILE_BYTES + wave * 1024 + lane * 16,
                dbufc + wave * 1024);
  __syncthreads();

  float c8[8];
  #pragma unroll
  for (int i = 0; i < 8; ++i) c8[i] = 0.f;

  const size_t obase0 = (size_t)(b * NN) * NCH + ch;

  #pragma unroll 1
  for (int g = 0; g < NGRP; ++g) {
    const int buf = g & 1;
    const unsigned char* bp = dbufc + buf * 4096;
    // Swizzled fragment addresses. NOTE: the XOR must be applied to the
    // full logical offset; since bit6 of the base is 0, (L+64)^s == ra^64.
    // (ra + 64 is WRONG: carries into the row bits when (lane&4) != 0.)
    const int ra = ((lane & 15) * 128 + (lane >> 4) * 16) ^ ((lane & 7) << 4);
    bf16x8 bh0 = *(const bf16x8*)(bp + ra);
    bf16x8 bh1 = *(const bf16x8*)(bp + (ra ^ 64));
    bf16x8 bl0 = *(const bf16x8*)(bp + 2048 + ra);
    bf16x8 bl1 = *(const bf16x8*)(bp + 2048 + (ra ^ 64));

    // issue next tile's async loads early (lands before end-of-group barrier)
    if (g + 1 < NGRP && wave < 4)
      GLOAD_LDS16(tiles + (size_t)(b * NGRP + g + 1) * TILE_BYTES + wave * 1024 + lane * 16,
                  dbufc + (buf ^ 1) * 4096 + wave * 1024);

    // merge previous group's wave partials (round-robin wave)
    if (g > 0 && wave == ((g - 1) & 7))
      merge8(sbuf[(g - 1) & 1], lane, part, obase0 + (size_t)((g - 1) * NB) * NCH);

    // bf16x3 MFMA: z = wH*dH + wH*dL + wL*dH
    f32x4 zz[2];
    zz[0] = (f32x4)(0.f); zz[1] = (f32x4)(0.f);
    zz[0] = __builtin_amdgcn_mfma_f32_16x16x32_bf16(aH[0][0], bh0, zz[0], 0, 0, 0);
    zz[0] = __builtin_amdgcn_mfma_f32_16x16x32_bf16(aH[0][0], bl0, zz[0], 0, 0, 0);
    zz[0] = __builtin_amdgcn_mfma_f32_16x16x32_bf16(aL[0][0], bh0, zz[0], 0, 0, 0);
    zz[0] = __builtin_amdgcn_mfma_f32_16x16x32_bf16(aH[0][1], bh1, zz[0], 0, 0, 0);
    zz[0] = __builtin_amdgcn_mfma_f32_16x16x32_bf16(aH[0][1], bl1, zz[0], 0, 0, 0);
    zz[0] = __builtin_amdgcn_mfma_f32_16x16x32_bf16(aL[0][1], bh1, zz[0], 0, 0, 0);
    zz[1] = __builtin_amdgcn_mfma_f32_16x16x32_bf16(aH[1][0], bh0, zz[1], 0, 0, 0);
    zz[1] = __builtin_amdgcn_mfma_f32_16x16x32_bf16(aH[1][0], bl0, zz[1], 0, 0, 0);
    zz[1] = __builtin_amdgcn_mfma_f32_16x16x32_bf16(aL[1][0], bh0, zz[1], 0, 0, 0);
    zz[1] = __builtin_amdgcn_mfma_f32_16x16x32_bf16(aH[1][1], bh1, zz[1], 0, 0, 0);
    zz[1] = __builtin_amdgcn_mfma_f32_16x16x32_bf16(aH[1][1], bl1, zz[1], 0, 0, 0);
    zz[1] = __builtin_amdgcn_mfma_f32_16x16x32_bf16(aL[1][1], bh1, zz[1], 0, 0, 0);

    const float tgf = tgl[g * 16 + (lane & 15)];

    // ---- scan + softmax (log2 space) ----
    float alpha[8];
    float mloc = -3.4e38f;
    #pragma unroll
    for (int tile = 0; tile < 2; ++tile) {
      #pragma unroll
      for (int r = 0; r < 4; ++r) {
        const int t8 = tile * 4 + r;
        const float z  = zz[tile][r];
        const float rr = tgf - z;
        const float lp = rr * rr * NHL2E;
        float x = lp;
        x += dppf<SHR1>(x);
        x += dppf<SHR2>(x);
        x += dppf<SHR4>(x);
        x += dppf<SHR8>(x);                 // inclusive prefix over 16 cols
        const float tot = bcast15(x);       // group total (LDS pipe)
        const float a_ = c8[t8] + (x - lp); // carry + exclusive prefix
        alpha[t8] = a_;
        c8[t8] += tot;
        mloc = fmaxf(mloc, a_);
      }
    }
    float m = fmaxf(mloc, __shfl_xor(mloc, 16));
    m = fmaxf(m, __shfl_xor(m, 32));
    float sv = 0.f, vv = 0.f;
    #pragma unroll
    for (int tile = 0; tile < 2; ++tile) {
      #pragma unroll
      for (int r = 0; r < 4; ++r) {
        const float p = __builtin_amdgcn_exp2f(alpha[tile * 4 + r] - m);
        sv += p;
        vv = fmaf(p, zz[tile][r], vv);
      }
    }
    sv += __shfl_xor(sv, 16); sv += __shfl_xor(sv, 32);
    vv += __shfl_xor(vv, 16); vv += __shfl_xor(vv, 32);
    if (lane < 16) {
      float2 lr;
      lr.x = m + __log2f(sv);
      lr.y = vv / sv;
      sbuf[buf][wave][lane] = lr;
    }

    __syncthreads();   // drains vmcnt (next tile) + makes sbuf visible
  }

  if (wave == ((NGRP - 1) & 7))
    merge8(sbuf[(NGRP - 1) & 1], lane, part, obase0 + (size_t)((NGRP - 1) * NB) * NCH);
}

// ---------------------------------------------------------------------------
// Phase 2: 2 threads per output, 8 contiguous chunk pairs each (64 B),
// pair-merged via shfl_xor(1). Each (L,R) partial == (m=L, s=1, v=R).
__global__ __launch_bounds__(256)
void mmse_phase2(const float* __restrict__ part, float* __restrict__ out)
{
  const int gid  = blockIdx.x * 256 + threadIdx.x;
  const int idx  = gid >> 1;          // = b*NN + n
  const int half = gid & 1;
  const float2* __restrict__ p = (const float2*)part + (size_t)idx * NCH + half * 8;
  float M = -3.4e38f, S = 0.f, V = 0.f;
  #pragma unroll
  for (int c = 0; c < 8; ++c) {
    const float2 q = p[c];
    const float mn = fmaxf(M, q.x);
    const float ea = __builtin_amdgcn_exp2f(M - mn);
    const float eb = __builtin_amdgcn_exp2f(q.x - mn);
    S = fmaf(S, ea, eb);
    V = fmaf(V, ea, q.y * eb);
    M = mn;
  }
  const float m2 = __shfl_xor(M, 1), s2 = __shfl_xor(S, 1), v2 = __shfl_xor(V, 1);
  const float mn = fmaxf(M, m2);
  const float ea = __builtin_amdgcn_exp2f(M - mn);
  const float eb = __builtin_amdgcn_exp2f(m2 - mn);
  S = fmaf(S, ea, s2 * eb);
  V = fmaf(V, ea, v2 * eb);
  if (half == 0) out[idx] = V / S;
}

extern "C" void kernel_launch(void* const* d_in, const int* in_sizes, int n_in,
                              void* d_out, int out_size, void* d_ws, size_t ws_size,
                              hipStream_t stream)
{
  const float* data      = (const float*)d_in[0];   // (64,256,64)
  const float* targets   = (const float*)d_in[1];   // (64,256)
  const float* task_pool = (const float*)d_in[2];   // (4096,64,1) == (T,D)
  float* out = (float*)d_out;                       // (64,256)

  unsigned char* tiles = (unsigned char*)d_ws;                 // 4 MB
  float* part = (float*)((unsigned char*)d_ws + TILES_BYTES);  // 2.1 MB

  hipLaunchKernelGGL(mmse_phase0, dim3(BB * NN * DD / 2 / 256), dim3(256), 0, stream,
                     data, tiles);
  hipLaunchKernelGGL(mmse_phase1, dim3(BB * NCH), dim3(THREADS), 0, stream,
                     tiles, targets, task_pool, part);
  hipLaunchKernelGGL(mmse_phase2, dim3(2 * BN / 256), dim3(256), 0, stream,
                     part, out);
}

// Round 8
// 120.341 us; speedup vs baseline: 6.4693x; 1.0157x over previous
//
#include <hip/hip_runtime.h>
#include <math.h>

// Problem constants
#define BB 64      // batches
#define NN 256     // sequence length
#define DD 64      // feature dim
#define TT 4096    // task pool size

// Tiling
#define NCH 16                 // t-chunks (blocks per batch)
#define CT (TT/NCH)            // 256 tasks per block
#define THREADS 512
#define WAVES 8                // each wave owns 32 tasks (2 MFMA row-tiles)
#define NB 16                  // n rows per group
#define NGRP (NN/NB)           // 16
#define BN (BB*NN)             // 16384 outputs

#define NHL2E (-0.72134752044448170368f)     // -0.5 * log2(e)

typedef __bf16 bf16x8 __attribute__((ext_vector_type(8)));
typedef float  f32x4  __attribute__((ext_vector_type(4)));

// DPP row_shr ctrl codes
#define SHR1 0x111
#define SHR2 0x112
#define SHR4 0x114
#define SHR8 0x118

template<int C>
__device__ __forceinline__ float dppf(float x) {
  return __int_as_float(__builtin_amdgcn_update_dpp(
      0, __float_as_int(x), C, 0xf, 0xf, true));
}

// broadcast lane15 of each 16-lane group (BitMode: and=0x10, or=0xF)
__device__ __forceinline__ float bcast15(float x) {
  return __int_as_float(__builtin_amdgcn_ds_swizzle(__float_as_int(x), 0x1F0));
}

__device__ __forceinline__ unsigned short f2bf(float f) {  // RNE f32->bf16
  unsigned int u = __float_as_uint(f);
  unsigned int r = u + 0x7FFFu + ((u >> 16) & 1u);
  return (unsigned short)(r >> 16);
}
__device__ __forceinline__ float bf2f(unsigned short h) {
  return __uint_as_float(((unsigned int)h) << 16);
}

#define GLOAD_LDS16(gp, lp_) \
  __builtin_amdgcn_global_load_lds((const __attribute__((address_space(1))) void*)(gp), \
                                   (__attribute__((address_space(3))) void*)(lp_), 16, 0, 0)

union FragU { unsigned int u[4]; bf16x8 v; };

// Merge the 8 wave-partials (packed L = m + log2 s, R = v/s) of one group.
// obase = float2 index of (b, n0, ch) in part. PLAIN stores: the kernel
// boundary before phase2 provides cross-XCD coherence (round-5-proven;
// agent-scope relaxed atomics demonstrably did NOT — round 7, absmax 15.4).
__device__ __forceinline__ void merge8(const float2 (*sb)[16], int lane,
                                       float2* __restrict__ part, size_t obase) {
  const int col = lane & 15;
  float2 p0 = sb[0][col];
  float M = p0.x, S = 1.f, V = p0.y;
  #pragma unroll
  for (int w = 1; w < WAVES; ++w) {
    float2 pw = sb[w][col];
    float mn = fmaxf(M, pw.x);
    float ea = __builtin_amdgcn_exp2f(M - mn);
    float eb = __builtin_amdgcn_exp2f(pw.x - mn);
    S = S * ea + eb;
    V = fmaf(V, ea, pw.y * eb);
    M = mn;
  }
  if (lane < 16) {
    float2 lr;
    lr.x = M + __log2f(S);
    lr.y = V / S;
    part[obase + (size_t)col * NCH] = lr;
  }
}

// ---------------------------------------------------------------------------
// Kernel 1: block = (batch b, chunk of 256 tasks).
//  - data f32 -> bf16 hi/lo split + XOR-swizzled LDS image, converted in-block
//    (global load for group g+1 issued before group g's compute, T14-style) --
//    this fuses what used to be a separate phase0 dispatch.
//  - tasks on MFMA C-rows, n on C-cols; log2-space logp; DPP inclusive scan
//    over the 16 n-cols + ds_swizzle lane15 broadcast for the carry.
//  - per-wave softmax partials merged across 8 waves in LDS; chunk partials
//    (L,R) written with plain stores; phase2 kernel merges the 16 chunks.
__global__ __launch_bounds__(THREADS, 4)
void mmse_phase1(const float* __restrict__ data,
                 const float* __restrict__ targets,
                 const float* __restrict__ Wp,     // (T, D) row-major
                 float2* __restrict__ part)        // (BN, NCH) packed (L,R)
{
  const int bx   = blockIdx.x;
  const int b    = bx >> 4;
  const int ch   = bx & 15;
  const int tid  = threadIdx.x;
  const int lane = tid & 63;
  const int wave = tid >> 6;

  __shared__ uint4  dbufq[2][256];          // 2 x 4 KB swizzled tile images
  __shared__ float  tgl[NN];                // targets for this batch
  __shared__ float2 sbuf[2][WAVES][16];     // wave partials (L, R)

  unsigned char* dbufc = (unsigned char*)dbufq;

  // ---- W fragments -> registers (hi/lo). A-layout: row=l&15, k=(l>>4)*8+j
  bf16x8 aH[2][2], aL[2][2];
  {
    const int tb = ch * CT + wave * 32;
    #pragma unroll
    for (int tile = 0; tile < 2; ++tile) {
      #pragma unroll
      for (int s = 0; s < 2; ++s) {
        const int row = tb + tile * 16 + (lane & 15);
        const int kb  = s * 32 + (lane >> 4) * 8;
        const float* wp = Wp + (size_t)row * DD + kb;
        FragU hu, lu;
        #pragma unroll
        for (int jj = 0; jj < 4; ++jj) {
          const float f0 = wp[2 * jj], f1 = wp[2 * jj + 1];
          const unsigned short h0 = f2bf(f0), h1 = f2bf(f1);
          const unsigned short g0 = f2bf(f0 - bf2f(h0)), g1 = f2bf(f1 - bf2f(h1));
          hu.u[jj] = (unsigned int)h0 | ((unsigned int)h1 << 16);
          lu.u[jj] = (unsigned int)g0 | ((unsigned int)g1 << 16);
        }
        aH[tile][s] = hu.v; aL[tile][s] = lu.v;
      }
    }
  }

  // stage targets (1 KB) via async global->LDS
  if (wave == 0)
    GLOAD_LDS16(targets + (size_t)b * NN + lane * 4, tgl);

  const float* __restrict__ dbase = data + (size_t)b * NN * DD;
  // staging coords: thread -> (n row sn, float2 k-slot sk2) of the 16x64 tile
  const int sn  = tid >> 5;          // 0..15
  const int sk2 = tid & 31;          // 0..31
  const int sphys = (sn * 128 + sk2 * 4) ^ ((sn & 7) << 4);

  // stage group 0 (load + convert + swizzled write)
  {
    const float2 q = *(const float2*)(dbase + (size_t)sn * DD + sk2 * 2);
    const unsigned short h0 = f2bf(q.x), h1 = f2bf(q.y);
    const unsigned short g0 = f2bf(q.x - bf2f(h0)), g1 = f2bf(q.y - bf2f(h1));
    *(unsigned int*)(dbufc + sphys)        = (unsigned int)h0 | ((unsigned int)h1 << 16);
    *(unsigned int*)(dbufc + 2048 + sphys) = (unsigned int)g0 | ((unsigned int)g1 << 16);
  }
  __syncthreads();

  float c8[8];
  #pragma unroll
  for (int i = 0; i < 8; ++i) c8[i] = 0.f;

  const size_t obase0 = (size_t)(b * NN) * NCH + ch;

  #pragma unroll 1
  for (int g = 0; g < NGRP; ++g) {
    const int buf = g & 1;
    const unsigned char* bp = dbufc + buf * 4096;
    // Swizzled fragment addresses; second k-half is ra^64 (NOT ra+64: the
    // add would carry into row bits when (lane&4) != 0).
    const int ra = ((lane & 15) * 128 + (lane >> 4) * 16) ^ ((lane & 7) << 4);
    bf16x8 bh0 = *(const bf16x8*)(bp + ra);
    bf16x8 bh1 = *(const bf16x8*)(bp + (ra ^ 64));
    bf16x8 bl0 = *(const bf16x8*)(bp + 2048 + ra);
    bf16x8 bl1 = *(const bf16x8*)(bp + 2048 + (ra ^ 64));

    // issue next group's global load early (hides HBM/L2 latency under MFMA)
    float2 q;
    if (g + 1 < NGRP)
      q = *(const float2*)(dbase + (size_t)((g + 1) * NB + sn) * DD + sk2 * 2);

    // merge previous group's wave partials (round-robin wave)
    if (g > 0 && wave == ((g - 1) & 7))
      merge8(sbuf[(g - 1) & 1], lane, part, obase0 + (size_t)((g - 1) * NB) * NCH);

    // bf16x3 MFMA: z = wH*dH + wH*dL + wL*dH
    f32x4 zz[2];
    zz[0] = (f32x4)(0.f); zz[1] = (f32x4)(0.f);
    zz[0] = __builtin_amdgcn_mfma_f32_16x16x32_bf16(aH[0][0], bh0, zz[0], 0, 0, 0);
    zz[0] = __builtin_amdgcn_mfma_f32_16x16x32_bf16(aH[0][0], bl0, zz[0], 0, 0, 0);
    zz[0] = __builtin_amdgcn_mfma_f32_16x16x32_bf16(aL[0][0], bh0, zz[0], 0, 0, 0);
    zz[0] = __builtin_amdgcn_mfma_f32_16x16x32_bf16(aH[0][1], bh1, zz[0], 0, 0, 0);
    zz[0] = __builtin_amdgcn_mfma_f32_16x16x32_bf16(aH[0][1], bl1, zz[0], 0, 0, 0);
    zz[0] = __builtin_amdgcn_mfma_f32_16x16x32_bf16(aL[0][1], bh1, zz[0], 0, 0, 0);
    zz[1] = __builtin_amdgcn_mfma_f32_16x16x32_bf16(aH[1][0], bh0, zz[1], 0, 0, 0);
    zz[1] = __builtin_amdgcn_mfma_f32_16x16x32_bf16(aH[1][0], bl0, zz[1], 0, 0, 0);
    zz[1] = __builtin_amdgcn_mfma_f32_16x16x32_bf16(aL[1][0], bh0, zz[1], 0, 0, 0);
    zz[1] = __builtin_amdgcn_mfma_f32_16x16x32_bf16(aH[1][1], bh1, zz[1], 0, 0, 0);
    zz[1] = __builtin_amdgcn_mfma_f32_16x16x32_bf16(aH[1][1], bl1, zz[1], 0, 0, 0);
    zz[1] = __builtin_amdgcn_mfma_f32_16x16x32_bf16(aL[1][1], bh1, zz[1], 0, 0, 0);

    const float tgf = tgl[g * 16 + (lane & 15)];

    // ---- scan + softmax (log2 space) ----
    float alpha[8];
    float mloc = -3.4e38f;
    #pragma unroll
    for (int tile = 0; tile < 2; ++tile) {
      #pragma unroll
      for (int r = 0; r < 4; ++r) {
        const int t8 = tile * 4 + r;
        const float z  = zz[tile][r];
        const float rr = tgf - z;
        const float lp = rr * rr * NHL2E;
        float x = lp;
        x += dppf<SHR1>(x);
        x += dppf<SHR2>(x);
        x += dppf<SHR4>(x);
        x += dppf<SHR8>(x);                 // inclusive prefix over 16 cols
        const float tot = bcast15(x);       // group total (LDS pipe)
        const float a_ = c8[t8] + (x - lp); // carry + exclusive prefix
        alpha[t8] = a_;
        c8[t8] += tot;
        mloc = fmaxf(mloc, a_);
      }
    }
    float m = fmaxf(mloc, __shfl_xor(mloc, 16));
    m = fmaxf(m, __shfl_xor(m, 32));
    float sv = 0.f, vv = 0.f;
    #pragma unroll
    for (int tile = 0; tile < 2; ++tile) {
      #pragma unroll
      for (int r = 0; r < 4; ++r) {
        const float p = __builtin_amdgcn_exp2f(alpha[tile * 4 + r] - m);
        sv += p;
        vv = fmaf(p, zz[tile][r], vv);
      }
    }
    sv += __shfl_xor(sv, 16); sv += __shfl_xor(sv, 32);
    vv += __shfl_xor(vv, 16); vv += __shfl_xor(vv, 32);
    if (lane < 16) {
      float2 lr;
      lr.x = m + __log2f(sv);
      lr.y = vv / sv;
      sbuf[buf][wave][lane] = lr;
    }

    // convert + swizzled write of next group into the other buffer
    if (g + 1 < NGRP) {
      const unsigned short h0 = f2bf(q.x), h1 = f2bf(q.y);
      const unsigned short g0 = f2bf(q.x - bf2f(h0)), g1 = f2bf(q.y - bf2f(h1));
      unsigned char* wb = dbufc + (buf ^ 1) * 4096;
      *(unsigned int*)(wb + sphys)        = (unsigned int)h0 | ((unsigned int)h1 << 16);
      *(unsigned int*)(wb + 2048 + sphys) = (unsigned int)g0 | ((unsigned int)g1 << 16);
    }
    __syncthreads();
  }

  if (wave == ((NGRP - 1) & 7))
    merge8(sbuf[(NGRP - 1) & 1], lane, part, obase0 + (size_t)((NGRP - 1) * NB) * NCH);
}

// ---------------------------------------------------------------------------
// Kernel 2: merge the NCH=16 chunk partials per output. 2 threads per output,
// 8 contiguous (L,R) pairs each (64 B), pair-merged via shfl_xor(1).
// Each (L,R) partial == (m=L, s=1, v=R).
__global__ __launch_bounds__(256)
void mmse_phase2(const float* __restrict__ part, float* __restrict__ out)
{
  const int gid  = blockIdx.x * 256 + threadIdx.x;
  const int idx  = gid >> 1;          // = b*NN + n
  const int half = gid & 1;
  const float2* __restrict__ p = (const float2*)part + (size_t)idx * NCH + half * 8;
  float M = -3.4e38f, S = 0.f, V = 0.f;
  #pragma unroll
  for (int c = 0; c < 8; ++c) {
    const float2 q = p[c];
    const float mn = fmaxf(M, q.x);
    const float ea = __builtin_amdgcn_exp2f(M - mn);
    const float eb = __builtin_amdgcn_exp2f(q.x - mn);
    S = fmaf(S, ea, eb);
    V = fmaf(V, ea, q.y * eb);
    M = mn;
  }
  const float m2 = __shfl_xor(M, 1), s2 = __shfl_xor(S, 1), v2 = __shfl_xor(V, 1);
  const float mn = fmaxf(M, m2);
  const float ea = __builtin_amdgcn_exp2f(M - mn);
  const float eb = __builtin_amdgcn_exp2f(m2 - mn);
  S = fmaf(S, ea, s2 * eb);
  V = fmaf(V, ea, v2 * eb);
  if (half == 0) out[idx] = V / S;
}

extern "C" void kernel_launch(void* const* d_in, const int* in_sizes, int n_in,
                              void* d_out, int out_size, void* d_ws, size_t ws_size,
                              hipStream_t stream)
{
  const float* data      = (const float*)d_in[0];   // (64,256,64)
  const float* targets   = (const float*)d_in[1];   // (64,256)
  const float* task_pool = (const float*)d_in[2];   // (4096,64,1) == (T,D)
  float* out = (float*)d_out;                       // (64,256)

  float2* part = (float2*)d_ws;                     // BN*NCH*8 = 2 MB

  hipLaunchKernelGGL(mmse_phase1, dim3(BB * NCH), dim3(THREADS), 0, stream,
                     data, targets, task_pool, part);
  hipLaunchKernelGGL(mmse_phase2, dim3(2 * BN / 256), dim3(256), 0, stream,
                     (const float*)part, out);
}

// Round 9
// 112.349 us; speedup vs baseline: 6.9294x; 1.0711x over previous
//
#include <hip/hip_runtime.h>
#include <math.h>

// Problem constants
#define BB 64      // batches
#define NN 256     // sequence length
#define DD 64      // feature dim
#define TT 4096    // task pool size

// Tiling
#define NCH 16                 // t-chunks (blocks per batch)
#define CT (TT/NCH)            // 256 tasks per block
#define THREADS 512
#define WAVES 8                // each wave owns 32 tasks (2 MFMA row-tiles)
#define NB 32                  // n rows per staged group (2 halves of 16)
#define NGRP (NN/NB)           // 8
#define BN (BB*NN)             // 16384 outputs

#define NHL2E (-0.72134752044448170368f)     // -0.5 * log2(e)

typedef __bf16 bf16x4 __attribute__((ext_vector_type(4)));
typedef __bf16 bf16x8 __attribute__((ext_vector_type(8)));
typedef float  f32x4  __attribute__((ext_vector_type(4)));

// DPP row_shr ctrl codes
#define SHR1 0x111
#define SHR2 0x112
#define SHR4 0x114
#define SHR8 0x118

template<int C>
__device__ __forceinline__ float dppf(float x) {
  return __int_as_float(__builtin_amdgcn_update_dpp(
      0, __float_as_int(x), C, 0xf, 0xf, true));
}

// broadcast lane15 of each 16-lane group (BitMode: and=0x10, or=0xF)
__device__ __forceinline__ float bcast15(float x) {
  return __int_as_float(__builtin_amdgcn_ds_swizzle(__float_as_int(x), 0x1F0));
}

#define GLOAD_LDS16(gp, lp_) \
  __builtin_amdgcn_global_load_lds((const __attribute__((address_space(1))) void*)(gp), \
                                   (__attribute__((address_space(3))) void*)(lp_), 16, 0, 0)

// Merge the 8 wave-partials (packed L = m + log2 s, R = v/s) of one group
// (32 n-cols). PLAIN stores: the kernel boundary before phase2 provides
// cross-XCD coherence (round-5-proven; agent-scope relaxed atomics did NOT).
__device__ __forceinline__ void merge32(const float2 (*sb)[NB], int lane,
                                        float2* __restrict__ part, size_t obase) {
  const int col = lane & 31;
  float2 p0 = sb[0][col];
  float M = p0.x, S = 1.f, V = p0.y;
  #pragma unroll
  for (int w = 1; w < WAVES; ++w) {
    float2 pw = sb[w][col];
    float mn = fmaxf(M, pw.x);
    float ea = __builtin_amdgcn_exp2f(M - mn);
    float eb = __builtin_amdgcn_exp2f(pw.x - mn);
    S = S * ea + eb;
    V = fmaf(V, ea, pw.y * eb);
    M = mn;
  }
  if (lane < 32) {
    float2 lr;
    lr.x = M + __log2f(S);
    lr.y = V / S;
    part[obase + (size_t)col * NCH] = lr;
  }
}

// ---------------------------------------------------------------------------
// Kernel 1: block = (batch b, chunk of 256 tasks). 8 groups of 32 n-rows,
// each group = two sequential 16-n halves sharing W fragments/accumulators
// (halves the per-group barrier/staging overhead vs NB=16).
//  - data f32 -> bf16 hi/lo split via native casts (v_cvt_pk_bf16_f32),
//    XOR-swizzled LDS image; float4 global load issued one group ahead.
//  - tasks on MFMA C-rows, n on C-cols; log2-space logp; DPP inclusive scan
//    over 16 n-cols + ds_swizzle lane15 broadcast for the carry.
//  - per-wave softmax partials merged across 8 waves in LDS (round-robin);
//    chunk partials (L,R) plain-stored; phase2 merges the 16 chunks.
__global__ __launch_bounds__(THREADS, 4)
void mmse_phase1(const float* __restrict__ data,
                 const float* __restrict__ targets,
                 const float* __restrict__ Wp,     // (T, D) row-major
                 float2* __restrict__ part)        // (BN, NCH) packed (L,R)
{
  const int bx   = blockIdx.x;
  const int b    = bx >> 4;
  const int ch   = bx & 15;
  const int tid  = threadIdx.x;
  const int lane = tid & 63;
  const int wave = tid >> 6;

  __shared__ uint4  dbufq[2][512];          // 2 x 8 KB swizzled tile images
  __shared__ float  tgl[NN];                // targets for this batch
  __shared__ float2 sbuf[2][WAVES][NB];     // wave partials (L, R)

  unsigned char* dbufc = (unsigned char*)dbufq;

  // ---- W fragments -> registers (hi/lo). A-layout: row=l&15, k=(l>>4)*8+j
  bf16x8 aH[2][2], aL[2][2];
  {
    const int tb = ch * CT + wave * 32;
    #pragma unroll
    for (int tile = 0; tile < 2; ++tile) {
      #pragma unroll
      for (int s = 0; s < 2; ++s) {
        const int row = tb + tile * 16 + (lane & 15);
        const int kb  = s * 32 + (lane >> 4) * 8;
        const float* wp = Wp + (size_t)row * DD + kb;
        const float4 qa = *(const float4*)wp;
        const float4 qb = *(const float4*)(wp + 4);
        float f[8] = {qa.x, qa.y, qa.z, qa.w, qb.x, qb.y, qb.z, qb.w};
        bf16x8 hv, lv;
        #pragma unroll
        for (int j = 0; j < 8; ++j) {
          const __bf16 hj = (__bf16)f[j];
          hv[j] = hj;
          lv[j] = (__bf16)(f[j] - (float)hj);
        }
        aH[tile][s] = hv; aL[tile][s] = lv;
      }
    }
  }

  // stage targets (1 KB) via async global->LDS
  if (wave == 0)
    GLOAD_LDS16(targets + (size_t)b * NN + lane * 4, tgl);

  const float* __restrict__ dbase = data + (size_t)b * NN * DD;
  // staging coords: thread -> (n row sn of 32, 16-byte... 4-float k-slot sk8)
  const int sn  = tid >> 4;          // 0..31
  const int sk8 = tid & 15;          // 0..15 (4 floats each)
  const int sphys = (sn * 128 + sk8 * 8) ^ ((sn & 7) << 4);   // 8B-aligned

  // stage group 0 (load + convert + swizzled write)
  {
    const float4 q = *(const float4*)(dbase + (size_t)sn * DD + sk8 * 4);
    float f[4] = {q.x, q.y, q.z, q.w};
    bf16x4 hv, lv;
    #pragma unroll
    for (int j = 0; j < 4; ++j) {
      const __bf16 hj = (__bf16)f[j];
      hv[j] = hj;
      lv[j] = (__bf16)(f[j] - (float)hj);
    }
    *(bf16x4*)(dbufc + sphys)        = hv;
    *(bf16x4*)(dbufc + 4096 + sphys) = lv;
  }
  __syncthreads();

  float c8[8];
  #pragma unroll
  for (int i = 0; i < 8; ++i) c8[i] = 0.f;

  const size_t obase0 = (size_t)(b * NN) * NCH + ch;
  // Swizzled fragment base; second k-step is ra^64 (NOT ra+64: the add
  // carries into row bits when (lane&4) != 0).
  const int ra = ((lane & 15) * 128 + (lane >> 4) * 16) ^ ((lane & 7) << 4);

  #pragma unroll 1
  for (int g = 0; g < NGRP; ++g) {
    const int buf = g & 1;
    const unsigned char* bp = dbufc + buf * 8192;

    // issue next group's global load early (hides HBM/L2 latency under MFMA)
    float4 q;
    if (g + 1 < NGRP)
      q = *(const float4*)(dbase + (size_t)((g + 1) * NB + sn) * DD + sk8 * 4);

    // merge previous group's wave partials (round-robin wave)
    if (g > 0 && wave == ((g - 1) & 7))
      merge32(sbuf[(g - 1) & 1], lane, part, obase0 + (size_t)((g - 1) * NB) * NCH);

    #pragma unroll
    for (int h = 0; h < 2; ++h) {
      const unsigned char* hp = bp + h * 2048;
      bf16x8 bh0 = *(const bf16x8*)(hp + ra);
      bf16x8 bh1 = *(const bf16x8*)(hp + (ra ^ 64));
      bf16x8 bl0 = *(const bf16x8*)(hp + 4096 + ra);
      bf16x8 bl1 = *(const bf16x8*)(hp + 4096 + (ra ^ 64));

      // bf16x3 MFMA: z = wH*dH + wH*dL + wL*dH
      f32x4 zz[2];
      zz[0] = (f32x4)(0.f); zz[1] = (f32x4)(0.f);
      __builtin_amdgcn_s_setprio(1);
      zz[0] = __builtin_amdgcn_mfma_f32_16x16x32_bf16(aH[0][0], bh0, zz[0], 0, 0, 0);
      zz[0] = __builtin_amdgcn_mfma_f32_16x16x32_bf16(aH[0][0], bl0, zz[0], 0, 0, 0);
      zz[0] = __builtin_amdgcn_mfma_f32_16x16x32_bf16(aL[0][0], bh0, zz[0], 0, 0, 0);
      zz[0] = __builtin_amdgcn_mfma_f32_16x16x32_bf16(aH[0][1], bh1, zz[0], 0, 0, 0);
      zz[0] = __builtin_amdgcn_mfma_f32_16x16x32_bf16(aH[0][1], bl1, zz[0], 0, 0, 0);
      zz[0] = __builtin_amdgcn_mfma_f32_16x16x32_bf16(aL[0][1], bh1, zz[0], 0, 0, 0);
      zz[1] = __builtin_amdgcn_mfma_f32_16x16x32_bf16(aH[1][0], bh0, zz[1], 0, 0, 0);
      zz[1] = __builtin_amdgcn_mfma_f32_16x16x32_bf16(aH[1][0], bl0, zz[1], 0, 0, 0);
      zz[1] = __builtin_amdgcn_mfma_f32_16x16x32_bf16(aL[1][0], bh0, zz[1], 0, 0, 0);
      zz[1] = __builtin_amdgcn_mfma_f32_16x16x32_bf16(aH[1][1], bh1, zz[1], 0, 0, 0);
      zz[1] = __builtin_amdgcn_mfma_f32_16x16x32_bf16(aH[1][1], bl1, zz[1], 0, 0, 0);
      zz[1] = __builtin_amdgcn_mfma_f32_16x16x32_bf16(aL[1][1], bh1, zz[1], 0, 0, 0);
      __builtin_amdgcn_s_setprio(0);

      const float tgf = tgl[g * NB + h * 16 + (lane & 15)];

      // ---- scan + softmax (log2 space) ----
      float alpha[8];
      float mloc = -3.4e38f;
      #pragma unroll
      for (int tile = 0; tile < 2; ++tile) {
        #pragma unroll
        for (int r = 0; r < 4; ++r) {
          const int t8 = tile * 4 + r;
          const float z  = zz[tile][r];
          const float rr = tgf - z;
          const float lp = rr * rr * NHL2E;
          float x = lp;
          x += dppf<SHR1>(x);
          x += dppf<SHR2>(x);
          x += dppf<SHR4>(x);
          x += dppf<SHR8>(x);                 // inclusive prefix over 16 cols
          const float tot = bcast15(x);       // group total (LDS pipe)
          const float a_ = c8[t8] + (x - lp); // carry + exclusive prefix
          alpha[t8] = a_;
          c8[t8] += tot;
          mloc = fmaxf(mloc, a_);
        }
      }
      float m = fmaxf(mloc, __shfl_xor(mloc, 16));
      m = fmaxf(m, __shfl_xor(m, 32));
      float sv = 0.f, vv = 0.f;
      #pragma unroll
      for (int tile = 0; tile < 2; ++tile) {
        #pragma unroll
        for (int r = 0; r < 4; ++r) {
          const float p = __builtin_amdgcn_exp2f(alpha[tile * 4 + r] - m);
          sv += p;
          vv = fmaf(p, zz[tile][r], vv);
        }
      }
      sv += __shfl_xor(sv, 16); sv += __shfl_xor(sv, 32);
      vv += __shfl_xor(vv, 16); vv += __shfl_xor(vv, 32);
      if (lane < 16) {
        float2 lr;
        lr.x = m + __log2f(sv);
        lr.y = vv / sv;
        sbuf[buf][wave][h * 16 + lane] = lr;
      }
    }

    // convert + swizzled write of next group into the other buffer
    if (g + 1 < NGRP) {
      float f[4] = {q.x, q.y, q.z, q.w};
      bf16x4 hv, lv;
      #pragma unroll
      for (int j = 0; j < 4; ++j) {
        const __bf16 hj = (__bf16)f[j];
        hv[j] = hj;
        lv[j] = (__bf16)(f[j] - (float)hj);
      }
      unsigned char* wb = dbufc + (buf ^ 1) * 8192;
      *(bf16x4*)(wb + sphys)        = hv;
      *(bf16x4*)(wb + 4096 + sphys) = lv;
    }
    __syncthreads();
  }

  if (wave == ((NGRP - 1) & 7))
    merge32(sbuf[(NGRP - 1) & 1], lane, part, obase0 + (size_t)((NGRP - 1) * NB) * NCH);
}

// ---------------------------------------------------------------------------
// Kernel 2: merge the NCH=16 chunk partials per output. 2 threads per output,
// 8 contiguous (L,R) pairs each (64 B), pair-merged via shfl_xor(1).
// Each (L,R) partial == (m=L, s=1, v=R).
__global__ __launch_bounds__(256)
void mmse_phase2(const float* __restrict__ part, float* __restrict__ out)
{
  const int gid  = blockIdx.x * 256 + threadIdx.x;
  const int idx  = gid >> 1;          // = b*NN + n
  const int half = gid & 1;
  const float2* __restrict__ p = (const float2*)part + (size_t)idx * NCH + half * 8;
  float M = -3.4e38f, S = 0.f, V = 0.f;
  #pragma unroll
  for (int c = 0; c < 8; ++c) {
    const float2 q = p[c];
    const float mn = fmaxf(M, q.x);
    const float ea = __builtin_amdgcn_exp2f(M - mn);
    const float eb = __builtin_amdgcn_exp2f(q.x - mn);
    S = fmaf(S, ea, eb);
    V = fmaf(V, ea, q.y * eb);
    M = mn;
  }
  const float m2 = __shfl_xor(M, 1), s2 = __shfl_xor(S, 1), v2 = __shfl_xor(V, 1);
  const float mn = fmaxf(M, m2);
  const float ea = __builtin_amdgcn_exp2f(M - mn);
  const float eb = __builtin_amdgcn_exp2f(m2 - mn);
  S = fmaf(S, ea, s2 * eb);
  V = fmaf(V, ea, v2 * eb);
  if (half == 0) out[idx] = V / S;
}

extern "C" void kernel_launch(void* const* d_in, const int* in_sizes, int n_in,
                              void* d_out, int out_size, void* d_ws, size_t ws_size,
                              hipStream_t stream)
{
  const float* data      = (const float*)d_in[0];   // (64,256,64)
  const float* targets   = (const float*)d_in[1];   // (64,256)
  const float* task_pool = (const float*)d_in[2];   // (4096,64,1) == (T,D)
  float* out = (float*)d_out;                       // (64,256)

  float2* part = (float2*)d_ws;                     // BN*NCH*8 = 2 MB

  hipLaunchKernelGGL(mmse_phase1, dim3(BB * NCH), dim3(THREADS), 0, stream,
                     data, targets, task_pool, part);
  hipLaunchKernelGGL(mmse_phase2, dim3(2 * BN / 256), dim3(256), 0, stream,
                     (const float*)part, out);
}